// Round 6
// baseline (258.838 us; speedup 1.0000x reference)
//
#include <hip/hip_runtime.h>
#include <hip/hip_bf16.h>

#define NTOK 2048
#define HDIM 1024
#define DDIM 1024
#define NEXP 8
#define MAXMB 40

typedef __bf16 bf16x8 __attribute__((ext_vector_type(8)));
typedef float f32x4 __attribute__((ext_vector_type(4)));

__device__ __forceinline__ f32x4 mfma16(bf16x8 a, bf16x8 b, f32x4 c) {
  return __builtin_amdgcn_mfma_f32_16x16x32_bf16(a, b, c, 0, 0, 0);
}

__device__ __forceinline__ void async_copy16(const void* g, void* l) {
  __builtin_amdgcn_global_load_lds(
      (const __attribute__((address_space(1))) void*)g,
      (__attribute__((address_space(3))) void*)l, 16, 0, 0);
}

// -------- transpose+convert, contiguity-first: [128k x 128n] tile per block ------------
// fp32 [E][1024][NC] -> bf16 [E][NC][1024]. Reads: 512B dense segments (half-wave per
// row-window). Writes: 256B dense per dst row (quarter-wave per row). REMAP (up_proj)
// is applied to the *store row address* only (pure row permutation), so reads stay
// contiguous: dst row for src col c: c<1024 -> (c>>6)*128+(c&63); else +64 variant.
// LDS: k-pairs in u32, U[64][132], XOR-4 swizzle on n -> conflict-free b128 writes.
template<int NC, bool REMAP>
__device__ __forceinline__ void tr_body(const float* __restrict__ src,
                                        __bf16* __restrict__ dst,
                                        int e, int kb, int cw,
                                        unsigned int (*U)[132])
{
  int t = threadIdx.x;
  int k0 = kb * 128;
  int c0 = cw * 128;
  const float* S = src + ((size_t)e * 1024 + k0) * NC + c0;
  int qp = t >> 5;          // 0..7
  int c4 = (t & 31) * 4;    // 0..124

#pragma unroll
  for (int sub = 0; sub < 2; ++sub) {
    f32x4 v0[4], v1[4];
#pragma unroll
    for (int rep = 0; rep < 4; ++rep) {
      int krel = sub * 64 + 2 * (rep * 8 + qp);
      v0[rep] = *(const f32x4*)(S + (size_t)krel * NC + c4);
      v1[rep] = *(const f32x4*)(S + (size_t)(krel + 1) * NC + c4);
    }
#pragma unroll
    for (int rep = 0; rep < 4; ++rep) {
      int q2 = sub * 32 + rep * 8 + qp;           // k-pair row 0..63
      union { unsigned int u; __bf16 h[2]; } p[4];
#pragma unroll
      for (int i = 0; i < 4; ++i) {
        p[i].h[0] = (__bf16)v0[rep][i];           // even k in low half
        p[i].h[1] = (__bf16)v1[rep][i];
      }
      int nsw = c4 ^ (4 * ((q2 >> 2) & 7));       // swizzled col base (aligned-4 safe)
      *(uint4*)&U[q2][nsw] = make_uint4(p[0].u, p[1].u, p[2].u, p[3].u);
    }
  }
  __syncthreads();

  int c = t & 15;           // k2-group: words 4c..4c+3 -> k = 8c..8c+8
  int nb = t >> 4;          // 0..15
  int X = 4 * (c & 7);      // read-side swizzle: (4c+i)>>2 & 7 == c&7 for i<4
#pragma unroll
  for (int j = 0; j < 8; ++j) {
    int n = nb + 16 * j;
    int nsw = n ^ X;
    unsigned int w0 = U[4 * c + 0][nsw];
    unsigned int w1 = U[4 * c + 1][nsw];
    unsigned int w2 = U[4 * c + 2][nsw];
    unsigned int w3 = U[4 * c + 3][nsw];
    int c_src = c0 + n;
    int r = REMAP ? (((c_src & 1023) >> 6) * 128 + ((c_src >> 10) & 1) * 64 + (c_src & 63))
                  : c_src;
    *(uint4*)(dst + ((size_t)e * NC + r) * 1024 + k0 + c * 8) =
        make_uint4(w0, w1, w2, w3);
  }
}

// up: 8 kb x 16 cw x 8 e = 1024 blocks | dn: 8 kb x 8 cw x 8 e = 512 blocks
__global__ __launch_bounds__(256) void transpose_kernel(
    const float* __restrict__ up, const float* __restrict__ dw,
    __bf16* __restrict__ wup, __bf16* __restrict__ wdn)
{
  __shared__ unsigned int U[64][132];   // 33792 B
  int bid = blockIdx.x;
  if (bid < 1024) {
    int kb = bid & 7, cw = (bid >> 3) & 15, e = bid >> 7;
    tr_body<2048, true>(up, wup, e, kb, cw, U);
  } else {
    int b = bid - 1024;
    int kb = b & 7, cw = (b >> 3) & 7, e = b >> 6;
    tr_body<1024, false>(dw, wdn, e, kb, cw, U);
  }
}

// -------- router: logits -> top2 -> expert lists; also x -> bf16 (4 tokens/block) -------
__global__ __launch_bounds__(256) void router_kernel(
    const float* __restrict__ x, const float* __restrict__ rw,
    __bf16* __restrict__ xb, int* __restrict__ counts,
    int* __restrict__ tok_list, float* __restrict__ wt_list)
{
  int wave = threadIdx.x >> 6, lane = threadIdx.x & 63;
  int n = blockIdx.x * 4 + wave;
  const float* xr = x + (size_t)n * HDIM;
  float acc[NEXP];
#pragma unroll
  for (int e = 0; e < NEXP; ++e) acc[e] = 0.f;
  float xv[16];
#pragma unroll
  for (int i = 0; i < 16; ++i) {
    int h = lane + 64 * i;
    float v = xr[h];
    xv[i] = v;
#pragma unroll
    for (int e = 0; e < NEXP; ++e) acc[e] += v * rw[e * HDIM + h];
  }
#pragma unroll
  for (int e = 0; e < NEXP; ++e) {
    float v = acc[e];
#pragma unroll
    for (int off = 32; off > 0; off >>= 1) v += __shfl_xor(v, off, 64);
    acc[e] = v;
  }
#pragma unroll
  for (int i = 0; i < 16; ++i)
    xb[(size_t)n * HDIM + lane + 64 * i] = (__bf16)xv[i];

  if (lane == 0) {
    int i1 = 0; float l1 = acc[0];
#pragma unroll
    for (int e = 1; e < NEXP; ++e) if (acc[e] > l1) { l1 = acc[e]; i1 = e; }
    int i2 = -1; float l2 = -3.4e38f;
#pragma unroll
    for (int e = 0; e < NEXP; ++e) if (e != i1 && acc[e] > l2) { l2 = acc[e]; i2 = e; }
    float m = fmaxf(l1, l2);
    float p1 = __expf(l1 - m), p2 = __expf(l2 - m);
    float inv = 1.f / (p1 + p2);
    int pos1 = atomicAdd(&counts[i1], 1);
    tok_list[i1 * NTOK + pos1] = n * 2;      // hidden row id = 2n + slot
    wt_list[i1 * NTOK + pos1] = p1 * inv;
    int pos2 = atomicAdd(&counts[i2], 1);
    tok_list[i2 * NTOK + pos2] = n * 2 + 1;
    wt_list[i2 * NTOK + pos2] = p2 * inv;
  }
}

// -------- m97-style gathered GEMM body: 128x128x64, inline (e,m0) scheduler -------------
// IS_UP: cols 0-63 = gate, 64-127 = up (same d range) -> SwiGLU in-lane; else down+atomic.
template<bool IS_UP>
__device__ __forceinline__ void gemm_body(
    const __bf16* __restrict__ Atok, const __bf16* __restrict__ Wt,
    const int* __restrict__ counts, const int* __restrict__ tok_list,
    const float* __restrict__ wt_list,
    __bf16* __restrict__ hidden, float* __restrict__ out,
    int mb, int n0, int kbeg, int kend,
    __bf16* As, __bf16* Bs, int* rows_s, float* wts_s)
{
  const int NC = IS_UP ? 2048 : 1024;
  int e = -1, m0 = 0, base = 0;
#pragma unroll
  for (int i = 0; i < NEXP; ++i) {
    int c = counts[i];
    int nt = (c + 127) >> 7;
    if (e < 0 && mb < base + nt) { e = i; m0 = (mb - base) << 7; }
    base += nt;
  }
  if (e < 0) return;
  int nrows = counts[e];

  int t = threadIdx.x;
  if (t < 128) {
    int idx = m0 + t;
    rows_s[t] = (idx < nrows) ? tok_list[e * NTOK + idx] : -1;
    wts_s[t] = (idx < nrows && !IS_UP) ? wt_list[e * NTOK + idx] : 0.f;
  }
  __syncthreads();

  int w = t >> 6, lane = t & 63;
  int lm = lane & 15, quad = lane >> 4;

  const __bf16* pA[4];
  const __bf16* pB[4];
#pragma unroll
  for (int j = 0; j < 4; ++j) {
    int s = j * 256 + t;
    int r = s >> 3;
    int cg = (s & 7) ^ (r & 7);
    int rid = rows_s[r];
    int arow = (rid < 0) ? 0 : (IS_UP ? (rid >> 1) : rid);
    pA[j] = Atok + (size_t)arow * 1024 + cg * 8;
    pB[j] = Wt + ((size_t)e * NC + n0 + r) * 1024 + cg * 8;
  }

  f32x4 acc[2][8];
#pragma unroll
  for (int i = 0; i < 2; ++i)
#pragma unroll
    for (int j = 0; j < 8; ++j) acc[i][j] = (f32x4){0.f, 0.f, 0.f, 0.f};

  for (int k0 = kbeg; k0 < kend; k0 += 64) {
#pragma unroll
    for (int j = 0; j < 4; ++j) {
      async_copy16(pA[j] + k0, (char*)As + (j * 256 + w * 64) * 16);
      async_copy16(pB[j] + k0, (char*)Bs + (j * 256 + w * 64) * 16);
    }
    __syncthreads();
#pragma unroll
    for (int kk = 0; kk < 2; ++kk) {
      bf16x8 a[2], b[8];
#pragma unroll
      for (int i = 0; i < 2; ++i) {
        int R = w * 32 + i * 16 + lm;
        int c = (quad + kk * 4) ^ (R & 7);
        a[i] = *(const bf16x8*)((char*)As + (size_t)(R * 8 + c) * 16);
      }
#pragma unroll
      for (int j = 0; j < 8; ++j) {
        int R = j * 16 + lm;
        int c = (quad + kk * 4) ^ (R & 7);
        b[j] = *(const bf16x8*)((char*)Bs + (size_t)(R * 8 + c) * 16);
      }
#pragma unroll
      for (int i = 0; i < 2; ++i)
#pragma unroll
        for (int j = 0; j < 8; ++j)
          acc[i][j] = mfma16(a[i], b[j], acc[i][j]);
    }
    __syncthreads();
  }

  if (IS_UP) {
    int dbase = n0 >> 1;   // 64 unique d per 128-wide tile
#pragma unroll
    for (int i = 0; i < 2; ++i)
#pragma unroll
      for (int j = 0; j < 4; ++j)
#pragma unroll
        for (int r = 0; r < 4; ++r) {
          int lr = w * 32 + i * 16 + quad * 4 + r;   // C/D: row = quad*4+reg
          int rid = rows_s[lr];
          if (rid >= 0) {
            float g = acc[i][j][r];
            float u = acc[i][j + 4][r];
            float hv = g / (1.f + __expf(-g)) * u;
            hidden[(size_t)rid * DDIM + dbase + j * 16 + lm] = (__bf16)hv;
          }
        }
  } else {
#pragma unroll
    for (int i = 0; i < 2; ++i)
#pragma unroll
      for (int j = 0; j < 8; ++j)
#pragma unroll
        for (int r = 0; r < 4; ++r) {
          int lr = w * 32 + i * 16 + quad * 4 + r;
          int rid = rows_s[lr];
          if (rid >= 0) {
            unsafeAtomicAdd(&out[(size_t)(rid >> 1) * HDIM + n0 + j * 16 + lm],
                            acc[i][j][r] * wts_s[lr]);
          }
        }
  }
}

// -------- up-GEMM: 640 blocks, ny = b&15 -> XCD = ny%8 (B-tile L2 locality) ------------
__global__ __launch_bounds__(256, 3) void up_kernel(
    const __bf16* __restrict__ xb, const __bf16* __restrict__ wup,
    const int* __restrict__ counts, const int* __restrict__ tok_list,
    const float* __restrict__ wt_list, __bf16* __restrict__ hidden)
{
  __shared__ __align__(16) char smem[33792];
  __bf16* As = (__bf16*)smem;
  __bf16* Bs = (__bf16*)(smem + 16384);
  int* rows_s = (int*)(smem + 32768);
  float* wts_s = (float*)(smem + 33280);
  int b = blockIdx.x;
  gemm_body<true>(xb, wup, counts, tok_list, wt_list, hidden, (float*)nullptr,
                  b >> 4, (b & 15) * 128, 0, 1024, As, Bs, rows_s, wts_s);
}

// -------- down: grid (8 ny, 40 mb, 2 kz) -> XCD = ny (B-tile L2 locality) --------------
__global__ __launch_bounds__(256, 3) void down_kernel(
    const __bf16* __restrict__ hidden, const __bf16* __restrict__ wdn,
    const int* __restrict__ counts, const int* __restrict__ tok_list,
    const float* __restrict__ wt_list, float* __restrict__ out)
{
  __shared__ __align__(16) char smem[33792];
  __bf16* As = (__bf16*)smem;
  __bf16* Bs = (__bf16*)(smem + 16384);
  int* rows_s = (int*)(smem + 32768);
  float* wts_s = (float*)(smem + 33280);
  int kz = blockIdx.z;
  gemm_body<false>(hidden, wdn, counts, tok_list, wt_list, (__bf16*)nullptr, out,
                   blockIdx.y, blockIdx.x * 128, kz * 512, kz * 512 + 512,
                   As, Bs, rows_s, wts_s);
}

extern "C" void kernel_launch(void* const* d_in, const int* in_sizes, int n_in,
                              void* d_out, int out_size, void* d_ws, size_t ws_size,
                              hipStream_t stream) {
  const float* x  = (const float*)d_in[0];
  const float* rw = (const float*)d_in[1];
  const float* up = (const float*)d_in[2];
  const float* dw = (const float*)d_in[3];
  float* out = (float*)d_out;

  char* ws = (char*)d_ws;
  int* counts    = (int*)ws;                                   // 32 B
  int* tok_list  = (int*)(ws + 4096);                          // 64 KB
  float* wt_list = (float*)(ws + 4096 + NEXP * NTOK * 4);      // 64 KB
  __bf16* xb     = (__bf16*)(ws + (1u << 20));                 // 4 MB  @ 1 MB
  __bf16* hidden = (__bf16*)(ws + (8u << 20));                 // 8 MB  @ 8 MB
  __bf16* wup    = (__bf16*)(ws + (16u << 20));                // 32 MB @ 16 MB
  __bf16* wdn    = (__bf16*)(ws + (48u << 20));                // 16 MB @ 48 MB
  (void)ws_size; (void)n_in; (void)in_sizes;

  hipMemsetAsync(counts, 0, NEXP * sizeof(int), stream);
  hipMemsetAsync(d_out, 0, (size_t)out_size * sizeof(float), stream);

  transpose_kernel<<<1536, 256, 0, stream>>>(up, dw, wup, wdn);
  router_kernel<<<512, 256, 0, stream>>>(x, rw, xb, counts, tok_list, wt_list);
  up_kernel<<<640, 256, 0, stream>>>(xb, wup, counts, tok_list, wt_list, hidden);
  down_kernel<<<dim3(8, MAXMB, 2), 256, 0, stream>>>(
      hidden, wdn, counts, tok_list, wt_list, out);
}

// Round 7
// 211.721 us; speedup vs baseline: 1.2225x; 1.2225x over previous
//
#include <hip/hip_runtime.h>
#include <hip/hip_bf16.h>

#define NTOK 2048
#define HDIM 1024
#define DDIM 1024
#define NEXP 8
#define MAXMB 40

typedef __bf16 bf16x8 __attribute__((ext_vector_type(8)));
typedef float f32x4 __attribute__((ext_vector_type(4)));

__device__ __forceinline__ f32x4 mfma16(bf16x8 a, bf16x8 b, f32x4 c) {
  return __builtin_amdgcn_mfma_f32_16x16x32_bf16(a, b, c, 0, 0, 0);
}

__device__ __forceinline__ void async_copy16(const void* g, void* l) {
  __builtin_amdgcn_global_load_lds(
      (const __attribute__((address_space(1))) void*)g,
      (__attribute__((address_space(3))) void*)l, 16, 0, 0);
}

// -------- transpose+convert, contiguity-first: [128k x 128n] tile per block ------------
// fp32 [E][1024][NC] -> bf16 [E][NC][1024]. Reads: 512B dense segments. Writes: 256B
// dense per dst row. REMAP (up_proj) applied to the *store row address* only.
// LDS: k-pairs in u32, U[64][132], XOR-4 swizzle on n -> conflict-free b128 writes.
template<int NC, bool REMAP>
__device__ __forceinline__ void tr_body(const float* __restrict__ src,
                                        __bf16* __restrict__ dst,
                                        int e, int kb, int cw,
                                        unsigned int (*U)[132])
{
  int t = threadIdx.x;
  int k0 = kb * 128;
  int c0 = cw * 128;
  const float* S = src + ((size_t)e * 1024 + k0) * NC + c0;
  int qp = t >> 5;          // 0..7
  int c4 = (t & 31) * 4;    // 0..124

#pragma unroll
  for (int sub = 0; sub < 2; ++sub) {
    f32x4 v0[4], v1[4];
#pragma unroll
    for (int rep = 0; rep < 4; ++rep) {
      int krel = sub * 64 + 2 * (rep * 8 + qp);
      v0[rep] = *(const f32x4*)(S + (size_t)krel * NC + c4);
      v1[rep] = *(const f32x4*)(S + (size_t)(krel + 1) * NC + c4);
    }
#pragma unroll
    for (int rep = 0; rep < 4; ++rep) {
      int q2 = sub * 32 + rep * 8 + qp;           // k-pair row 0..63
      union { unsigned int u; __bf16 h[2]; } p[4];
#pragma unroll
      for (int i = 0; i < 4; ++i) {
        p[i].h[0] = (__bf16)v0[rep][i];           // even k in low half
        p[i].h[1] = (__bf16)v1[rep][i];
      }
      int nsw = c4 ^ (4 * ((q2 >> 2) & 7));       // swizzled col base (aligned-4 safe)
      *(uint4*)&U[q2][nsw] = make_uint4(p[0].u, p[1].u, p[2].u, p[3].u);
    }
  }
  __syncthreads();

  int c = t & 15;           // words 4c..4c+3 -> k = 8c..8c+8
  int nb = t >> 4;          // 0..15
  int X = 4 * (c & 7);      // read-side swizzle
#pragma unroll
  for (int j = 0; j < 8; ++j) {
    int n = nb + 16 * j;
    int nsw = n ^ X;
    unsigned int w0 = U[4 * c + 0][nsw];
    unsigned int w1 = U[4 * c + 1][nsw];
    unsigned int w2 = U[4 * c + 2][nsw];
    unsigned int w3 = U[4 * c + 3][nsw];
    int c_src = c0 + n;
    int r = REMAP ? (((c_src & 1023) >> 6) * 128 + ((c_src >> 10) & 1) * 64 + (c_src & 63))
                  : c_src;
    *(uint4*)(dst + ((size_t)e * NC + r) * 1024 + k0 + c * 8) =
        make_uint4(w0, w1, w2, w3);
  }
}

// -------- fused prep: transpose [0,1536) | router (no atomics) [1536,2048) -------------
// Router writes per-token packed top-2 (e1|e2<<8) + weights; compaction is a separate
// tiny kernel with LDS atomics (kills the 54us global same-line atomic serialization).
__global__ __launch_bounds__(256) void prep_kernel(
    const float* __restrict__ x, const float* __restrict__ rw,
    const float* __restrict__ up, const float* __restrict__ dw,
    __bf16* __restrict__ xb, __bf16* __restrict__ wup, __bf16* __restrict__ wdn,
    unsigned int* __restrict__ top_pack, float2* __restrict__ top_w)
{
  __shared__ unsigned int U[64][132];   // 33792 B
  int bid = blockIdx.x;
  if (bid < 1024) {
    int kb = bid & 7, cw = (bid >> 3) & 15, e = bid >> 7;
    tr_body<2048, true>(up, wup, e, kb, cw, U);
    return;
  }
  if (bid < 1536) {
    int b = bid - 1024;
    int kb = b & 7, cw = (b >> 3) & 7, e = b >> 6;
    tr_body<1024, false>(dw, wdn, e, kb, cw, U);
    return;
  }
  // router: 4 tokens per block, one per wave
  int wave = threadIdx.x >> 6, lane = threadIdx.x & 63;
  int n = (bid - 1536) * 4 + wave;
  const float* xr = x + (size_t)n * HDIM;
  float acc[NEXP];
#pragma unroll
  for (int e = 0; e < NEXP; ++e) acc[e] = 0.f;
  float xv[16];
#pragma unroll
  for (int i = 0; i < 16; ++i) {
    int h = lane + 64 * i;
    float v = xr[h];
    xv[i] = v;
#pragma unroll
    for (int e = 0; e < NEXP; ++e) acc[e] += v * rw[e * HDIM + h];
  }
#pragma unroll
  for (int e = 0; e < NEXP; ++e) {
    float v = acc[e];
#pragma unroll
    for (int off = 32; off > 0; off >>= 1) v += __shfl_xor(v, off, 64);
    acc[e] = v;
  }
#pragma unroll
  for (int i = 0; i < 16; ++i)
    xb[(size_t)n * HDIM + lane + 64 * i] = (__bf16)xv[i];

  if (lane == 0) {
    int i1 = 0; float l1 = acc[0];
#pragma unroll
    for (int e = 1; e < NEXP; ++e) if (acc[e] > l1) { l1 = acc[e]; i1 = e; }
    int i2 = -1; float l2 = -3.4e38f;
#pragma unroll
    for (int e = 0; e < NEXP; ++e) if (e != i1 && acc[e] > l2) { l2 = acc[e]; i2 = e; }
    float m = fmaxf(l1, l2);
    float p1 = __expf(l1 - m), p2 = __expf(l2 - m);
    float inv = 1.f / (p1 + p2);
    top_pack[n] = (unsigned int)i1 | ((unsigned int)i2 << 8);
    top_w[n] = make_float2(p1 * inv, p2 * inv);
  }
}

// -------- compact: single block, LDS atomics -> counts + expert lists -------------------
__global__ __launch_bounds__(256) void compact_kernel(
    const unsigned int* __restrict__ top_pack, const float2* __restrict__ top_w,
    int* __restrict__ counts, int* __restrict__ tok_list, float* __restrict__ wt_list)
{
  __shared__ int cnt[NEXP];
  int t = threadIdx.x;
  if (t < NEXP) cnt[t] = 0;
  __syncthreads();
  for (int n = t; n < NTOK; n += 256) {
    unsigned int p = top_pack[n];
    float2 w = top_w[n];
    int e1 = p & 255, e2 = (p >> 8) & 255;
    int pos1 = atomicAdd(&cnt[e1], 1);
    tok_list[e1 * NTOK + pos1] = n * 2;        // hidden row id = 2n + slot
    wt_list[e1 * NTOK + pos1] = w.x;
    int pos2 = atomicAdd(&cnt[e2], 1);
    tok_list[e2 * NTOK + pos2] = n * 2 + 1;
    wt_list[e2 * NTOK + pos2] = w.y;
  }
  __syncthreads();
  if (t < NEXP) counts[t] = cnt[t];
}

// -------- m97-style gathered GEMM body: 128x128x64, inline (e,m0) scheduler -------------
// IS_UP: cols 0-63 = gate, 64-127 = up (same d range) -> SwiGLU in-lane; else down+atomic.
template<bool IS_UP>
__device__ __forceinline__ void gemm_body(
    const __bf16* __restrict__ Atok, const __bf16* __restrict__ Wt,
    const int* __restrict__ counts, const int* __restrict__ tok_list,
    const float* __restrict__ wt_list,
    __bf16* __restrict__ hidden, float* __restrict__ out,
    int mb, int n0, int kbeg, int kend,
    __bf16* As, __bf16* Bs, int* rows_s, float* wts_s)
{
  const int NC = IS_UP ? 2048 : 1024;
  int e = -1, m0 = 0, base = 0;
#pragma unroll
  for (int i = 0; i < NEXP; ++i) {
    int c = counts[i];
    int nt = (c + 127) >> 7;
    if (e < 0 && mb < base + nt) { e = i; m0 = (mb - base) << 7; }
    base += nt;
  }
  if (e < 0) return;
  int nrows = counts[e];

  int t = threadIdx.x;
  if (t < 128) {
    int idx = m0 + t;
    rows_s[t] = (idx < nrows) ? tok_list[e * NTOK + idx] : -1;
    wts_s[t] = (idx < nrows && !IS_UP) ? wt_list[e * NTOK + idx] : 0.f;
  }
  __syncthreads();

  int w = t >> 6, lane = t & 63;
  int lm = lane & 15, quad = lane >> 4;

  const __bf16* pA[4];
  const __bf16* pB[4];
#pragma unroll
  for (int j = 0; j < 4; ++j) {
    int s = j * 256 + t;
    int r = s >> 3;
    int cg = (s & 7) ^ (r & 7);
    int rid = rows_s[r];
    int arow = (rid < 0) ? 0 : (IS_UP ? (rid >> 1) : rid);
    pA[j] = Atok + (size_t)arow * 1024 + cg * 8;
    pB[j] = Wt + ((size_t)e * NC + n0 + r) * 1024 + cg * 8;
  }

  f32x4 acc[2][8];
#pragma unroll
  for (int i = 0; i < 2; ++i)
#pragma unroll
    for (int j = 0; j < 8; ++j) acc[i][j] = (f32x4){0.f, 0.f, 0.f, 0.f};

  for (int k0 = kbeg; k0 < kend; k0 += 64) {
#pragma unroll
    for (int j = 0; j < 4; ++j) {
      async_copy16(pA[j] + k0, (char*)As + (j * 256 + w * 64) * 16);
      async_copy16(pB[j] + k0, (char*)Bs + (j * 256 + w * 64) * 16);
    }
    __syncthreads();
#pragma unroll
    for (int kk = 0; kk < 2; ++kk) {
      bf16x8 a[2], b[8];
#pragma unroll
      for (int i = 0; i < 2; ++i) {
        int R = w * 32 + i * 16 + lm;
        int c = (quad + kk * 4) ^ (R & 7);
        a[i] = *(const bf16x8*)((char*)As + (size_t)(R * 8 + c) * 16);
      }
#pragma unroll
      for (int j = 0; j < 8; ++j) {
        int R = j * 16 + lm;
        int c = (quad + kk * 4) ^ (R & 7);
        b[j] = *(const bf16x8*)((char*)Bs + (size_t)(R * 8 + c) * 16);
      }
#pragma unroll
      for (int i = 0; i < 2; ++i)
#pragma unroll
        for (int j = 0; j < 8; ++j)
          acc[i][j] = mfma16(a[i], b[j], acc[i][j]);
    }
    __syncthreads();
  }

  if (IS_UP) {
    int dbase = n0 >> 1;   // 64 unique d per 128-wide tile
#pragma unroll
    for (int i = 0; i < 2; ++i)
#pragma unroll
      for (int j = 0; j < 4; ++j)
#pragma unroll
        for (int r = 0; r < 4; ++r) {
          int lr = w * 32 + i * 16 + quad * 4 + r;   // C/D: row = quad*4+reg
          int rid = rows_s[lr];
          if (rid >= 0) {
            float g = acc[i][j][r];
            float u = acc[i][j + 4][r];
            float hv = g / (1.f + __expf(-g)) * u;
            hidden[(size_t)rid * DDIM + dbase + j * 16 + lm] = (__bf16)hv;
          }
        }
  } else {
#pragma unroll
    for (int i = 0; i < 2; ++i)
#pragma unroll
      for (int j = 0; j < 8; ++j)
#pragma unroll
        for (int r = 0; r < 4; ++r) {
          int lr = w * 32 + i * 16 + quad * 4 + r;
          int rid = rows_s[lr];
          if (rid >= 0) {
            unsafeAtomicAdd(&out[(size_t)(rid >> 1) * HDIM + n0 + j * 16 + lm],
                            acc[i][j][r] * wts_s[lr]);
          }
        }
  }
}

// -------- up-GEMM: 640 blocks, ny = b&15 -> XCD = ny%8 (B-tile L2 locality) ------------
__global__ __launch_bounds__(256, 3) void up_kernel(
    const __bf16* __restrict__ xb, const __bf16* __restrict__ wup,
    const int* __restrict__ counts, const int* __restrict__ tok_list,
    const float* __restrict__ wt_list, __bf16* __restrict__ hidden)
{
  __shared__ __align__(16) char smem[33792];
  __bf16* As = (__bf16*)smem;
  __bf16* Bs = (__bf16*)(smem + 16384);
  int* rows_s = (int*)(smem + 32768);
  float* wts_s = (float*)(smem + 33280);
  int b = blockIdx.x;
  gemm_body<true>(xb, wup, counts, tok_list, wt_list, hidden, (float*)nullptr,
                  b >> 4, (b & 15) * 128, 0, 1024, As, Bs, rows_s, wts_s);
}

// -------- down: grid (8 ny, 40 mb, 2 kz) -> XCD = ny (B-tile L2 locality) --------------
__global__ __launch_bounds__(256, 3) void down_kernel(
    const __bf16* __restrict__ hidden, const __bf16* __restrict__ wdn,
    const int* __restrict__ counts, const int* __restrict__ tok_list,
    const float* __restrict__ wt_list, float* __restrict__ out)
{
  __shared__ __align__(16) char smem[33792];
  __bf16* As = (__bf16*)smem;
  __bf16* Bs = (__bf16*)(smem + 16384);
  int* rows_s = (int*)(smem + 32768);
  float* wts_s = (float*)(smem + 33280);
  int kz = blockIdx.z;
  gemm_body<false>(hidden, wdn, counts, tok_list, wt_list, (__bf16*)nullptr, out,
                   blockIdx.y, blockIdx.x * 128, kz * 512, kz * 512 + 512,
                   As, Bs, rows_s, wts_s);
}

extern "C" void kernel_launch(void* const* d_in, const int* in_sizes, int n_in,
                              void* d_out, int out_size, void* d_ws, size_t ws_size,
                              hipStream_t stream) {
  const float* x  = (const float*)d_in[0];
  const float* rw = (const float*)d_in[1];
  const float* up = (const float*)d_in[2];
  const float* dw = (const float*)d_in[3];
  float* out = (float*)d_out;

  char* ws = (char*)d_ws;
  int* counts          = (int*)ws;                             // 32 B
  int* tok_list        = (int*)(ws + 4096);                    // 64 KB
  float* wt_list       = (float*)(ws + 4096 + NEXP * NTOK * 4);// 64 KB
  unsigned int* top_pk = (unsigned int*)(ws + (256u << 10));   // 8 KB  @ 256 KB
  float2* top_w        = (float2*)(ws + (272u << 10));         // 16 KB @ 272 KB
  __bf16* xb           = (__bf16*)(ws + (1u << 20));           // 4 MB  @ 1 MB
  __bf16* hidden       = (__bf16*)(ws + (8u << 20));           // 8 MB  @ 8 MB
  __bf16* wup          = (__bf16*)(ws + (16u << 20));          // 32 MB @ 16 MB
  __bf16* wdn          = (__bf16*)(ws + (48u << 20));          // 16 MB @ 48 MB
  (void)ws_size; (void)n_in; (void)in_sizes;

  hipMemsetAsync(d_out, 0, (size_t)out_size * sizeof(float), stream);

  prep_kernel<<<2048, 256, 0, stream>>>(x, rw, up, dw, xb, wup, wdn, top_pk, top_w);
  compact_kernel<<<1, 256, 0, stream>>>(top_pk, top_w, counts, tok_list, wt_list);
  up_kernel<<<640, 256, 0, stream>>>(xb, wup, counts, tok_list, wt_list, hidden);
  down_kernel<<<dim3(8, MAXMB, 2), 256, 0, stream>>>(
      hidden, wdn, counts, tok_list, wt_list, out);
}

// Round 8
// 201.783 us; speedup vs baseline: 1.2828x; 1.0493x over previous
//
#include <hip/hip_runtime.h>
#include <hip/hip_bf16.h>

#define NTOK 2048
#define HDIM 1024
#define DDIM 1024
#define NEXP 8
#define MAXMB 40

typedef __bf16 bf16x8 __attribute__((ext_vector_type(8)));
typedef float f32x4 __attribute__((ext_vector_type(4)));

__device__ __forceinline__ f32x4 mfma16(bf16x8 a, bf16x8 b, f32x4 c) {
  return __builtin_amdgcn_mfma_f32_16x16x32_bf16(a, b, c, 0, 0, 0);
}

__device__ __forceinline__ void async_copy16(const void* g, void* l) {
  __builtin_amdgcn_global_load_lds(
      (const __attribute__((address_space(1))) void*)g,
      (__attribute__((address_space(3))) void*)l, 16, 0, 0);
}

// -------- transpose+convert, contiguity-first: [128k x 128n] tile per block ------------
// fp32 [E][1024][NC] -> bf16 [E][NC][1024]. Reads: 512B dense segments. Writes: 256B
// dense per dst row. REMAP (up_proj) applied to the *store row address* only.
// LDS: k-pairs in u32, U[64][132], XOR-4 swizzle on n -> conflict-free b128 writes.
template<int NC, bool REMAP>
__device__ __forceinline__ void tr_body(const float* __restrict__ src,
                                        __bf16* __restrict__ dst,
                                        int e, int kb, int cw,
                                        unsigned int (*U)[132])
{
  int t = threadIdx.x;
  int k0 = kb * 128;
  int c0 = cw * 128;
  const float* S = src + ((size_t)e * 1024 + k0) * NC + c0;
  int qp = t >> 5;          // 0..7
  int c4 = (t & 31) * 4;    // 0..124

#pragma unroll
  for (int sub = 0; sub < 2; ++sub) {
    f32x4 v0[4], v1[4];
#pragma unroll
    for (int rep = 0; rep < 4; ++rep) {
      int krel = sub * 64 + 2 * (rep * 8 + qp);
      v0[rep] = *(const f32x4*)(S + (size_t)krel * NC + c4);
      v1[rep] = *(const f32x4*)(S + (size_t)(krel + 1) * NC + c4);
    }
#pragma unroll
    for (int rep = 0; rep < 4; ++rep) {
      int q2 = sub * 32 + rep * 8 + qp;           // k-pair row 0..63
      union { unsigned int u; __bf16 h[2]; } p[4];
#pragma unroll
      for (int i = 0; i < 4; ++i) {
        p[i].h[0] = (__bf16)v0[rep][i];           // even k in low half
        p[i].h[1] = (__bf16)v1[rep][i];
      }
      int nsw = c4 ^ (4 * ((q2 >> 2) & 7));       // swizzled col base (aligned-4 safe)
      *(uint4*)&U[q2][nsw] = make_uint4(p[0].u, p[1].u, p[2].u, p[3].u);
    }
  }
  __syncthreads();

  int c = t & 15;           // words 4c..4c+3 -> k = 8c..8c+8
  int nb = t >> 4;          // 0..15
  int X = 4 * (c & 7);      // read-side swizzle
#pragma unroll
  for (int j = 0; j < 8; ++j) {
    int n = nb + 16 * j;
    int nsw = n ^ X;
    unsigned int w0 = U[4 * c + 0][nsw];
    unsigned int w1 = U[4 * c + 1][nsw];
    unsigned int w2 = U[4 * c + 2][nsw];
    unsigned int w3 = U[4 * c + 3][nsw];
    int c_src = c0 + n;
    int r = REMAP ? (((c_src & 1023) >> 6) * 128 + ((c_src >> 10) & 1) * 64 + (c_src & 63))
                  : c_src;
    *(uint4*)(dst + ((size_t)e * NC + r) * 1024 + k0 + c * 8) =
        make_uint4(w0, w1, w2, w3);
  }
}

// -------- fused prep: transpose [0,1536) | router (no atomics) [1536,2048) -------------
__global__ __launch_bounds__(256) void prep_kernel(
    const float* __restrict__ x, const float* __restrict__ rw,
    const float* __restrict__ up, const float* __restrict__ dw,
    __bf16* __restrict__ xb, __bf16* __restrict__ wup, __bf16* __restrict__ wdn,
    unsigned int* __restrict__ top_pack, float2* __restrict__ top_w)
{
  __shared__ unsigned int U[64][132];   // 33792 B
  int bid = blockIdx.x;
  if (bid < 1024) {
    int kb = bid & 7, cw = (bid >> 3) & 15, e = bid >> 7;
    tr_body<2048, true>(up, wup, e, kb, cw, U);
    return;
  }
  if (bid < 1536) {
    int b = bid - 1024;
    int kb = b & 7, cw = (b >> 3) & 7, e = b >> 6;
    tr_body<1024, false>(dw, wdn, e, kb, cw, U);
    return;
  }
  // router: 4 tokens per block, one per wave
  int wave = threadIdx.x >> 6, lane = threadIdx.x & 63;
  int n = (bid - 1536) * 4 + wave;
  const float* xr = x + (size_t)n * HDIM;
  float acc[NEXP];
#pragma unroll
  for (int e = 0; e < NEXP; ++e) acc[e] = 0.f;
  float xv[16];
#pragma unroll
  for (int i = 0; i < 16; ++i) {
    int h = lane + 64 * i;
    float v = xr[h];
    xv[i] = v;
#pragma unroll
    for (int e = 0; e < NEXP; ++e) acc[e] += v * rw[e * HDIM + h];
  }
#pragma unroll
  for (int e = 0; e < NEXP; ++e) {
    float v = acc[e];
#pragma unroll
    for (int off = 32; off > 0; off >>= 1) v += __shfl_xor(v, off, 64);
    acc[e] = v;
  }
#pragma unroll
  for (int i = 0; i < 16; ++i)
    xb[(size_t)n * HDIM + lane + 64 * i] = (__bf16)xv[i];

  if (lane == 0) {
    int i1 = 0; float l1 = acc[0];
#pragma unroll
    for (int e = 1; e < NEXP; ++e) if (acc[e] > l1) { l1 = acc[e]; i1 = e; }
    int i2 = -1; float l2 = -3.4e38f;
#pragma unroll
    for (int e = 0; e < NEXP; ++e) if (e != i1 && acc[e] > l2) { l2 = acc[e]; i2 = e; }
    float m = fmaxf(l1, l2);
    float p1 = __expf(l1 - m), p2 = __expf(l2 - m);
    float inv = 1.f / (p1 + p2);
    top_pack[n] = (unsigned int)i1 | ((unsigned int)i2 << 8);
    top_w[n] = make_float2(p1 * inv, p2 * inv);
  }
}

// -------- compact: one block per expert, LDS counter -> counts + tok_list ---------------
// List order is irrelevant (weights are applied per-token in combine), so per-block
// LDS atomics give valid positions with zero global atomics.
__global__ __launch_bounds__(256) void compact_kernel(
    const unsigned int* __restrict__ top_pack,
    int* __restrict__ counts, int* __restrict__ tok_list)
{
  int e = blockIdx.x;
  __shared__ int cnt;
  if (threadIdx.x == 0) cnt = 0;
  __syncthreads();
  for (int n = threadIdx.x; n < NTOK; n += 256) {
    unsigned int p = top_pack[n];
    int e1 = p & 255, e2 = (p >> 8) & 255;
    if (e1 == e) { int pos = atomicAdd(&cnt, 1); tok_list[e * NTOK + pos] = 2 * n; }
    if (e2 == e) { int pos = atomicAdd(&cnt, 1); tok_list[e * NTOK + pos] = 2 * n + 1; }
  }
  __syncthreads();
  if (threadIdx.x == 0) counts[e] = cnt;
}

// -------- m97-style gathered GEMM body: 128x128x64, inline (e,m0) scheduler -------------
// IS_UP: cols 0-63 = gate, 64-127 = up (same d range) -> SwiGLU in-lane -> hidden bf16.
// !IS_UP: plain stores of fp32 partials to D2[rid][h] (rid unique -> NO atomics).
template<bool IS_UP>
__device__ __forceinline__ void gemm_body(
    const __bf16* __restrict__ Atok, const __bf16* __restrict__ Wt,
    const int* __restrict__ counts, const int* __restrict__ tok_list,
    __bf16* __restrict__ hidden, float* __restrict__ out,
    int mb, int n0, int kbeg, int kend,
    __bf16* As, __bf16* Bs, int* rows_s)
{
  const int NC = IS_UP ? 2048 : 1024;
  int e = -1, m0 = 0, base = 0;
#pragma unroll
  for (int i = 0; i < NEXP; ++i) {
    int c = counts[i];
    int nt = (c + 127) >> 7;
    if (e < 0 && mb < base + nt) { e = i; m0 = (mb - base) << 7; }
    base += nt;
  }
  if (e < 0) return;
  int nrows = counts[e];

  int t = threadIdx.x;
  if (t < 128) {
    int idx = m0 + t;
    rows_s[t] = (idx < nrows) ? tok_list[e * NTOK + idx] : -1;
  }
  __syncthreads();

  int w = t >> 6, lane = t & 63;
  int lm = lane & 15, quad = lane >> 4;

  const __bf16* pA[4];
  const __bf16* pB[4];
#pragma unroll
  for (int j = 0; j < 4; ++j) {
    int s = j * 256 + t;
    int r = s >> 3;
    int cg = (s & 7) ^ (r & 7);
    int rid = rows_s[r];
    int arow = (rid < 0) ? 0 : (IS_UP ? (rid >> 1) : rid);
    pA[j] = Atok + (size_t)arow * 1024 + cg * 8;
    pB[j] = Wt + ((size_t)e * NC + n0 + r) * 1024 + cg * 8;
  }

  f32x4 acc[2][8];
#pragma unroll
  for (int i = 0; i < 2; ++i)
#pragma unroll
    for (int j = 0; j < 8; ++j) acc[i][j] = (f32x4){0.f, 0.f, 0.f, 0.f};

  for (int k0 = kbeg; k0 < kend; k0 += 64) {
#pragma unroll
    for (int j = 0; j < 4; ++j) {
      async_copy16(pA[j] + k0, (char*)As + (j * 256 + w * 64) * 16);
      async_copy16(pB[j] + k0, (char*)Bs + (j * 256 + w * 64) * 16);
    }
    __syncthreads();
#pragma unroll
    for (int kk = 0; kk < 2; ++kk) {
      bf16x8 a[2], b[8];
#pragma unroll
      for (int i = 0; i < 2; ++i) {
        int R = w * 32 + i * 16 + lm;
        int c = (quad + kk * 4) ^ (R & 7);
        a[i] = *(const bf16x8*)((char*)As + (size_t)(R * 8 + c) * 16);
      }
#pragma unroll
      for (int j = 0; j < 8; ++j) {
        int R = j * 16 + lm;
        int c = (quad + kk * 4) ^ (R & 7);
        b[j] = *(const bf16x8*)((char*)Bs + (size_t)(R * 8 + c) * 16);
      }
#pragma unroll
      for (int i = 0; i < 2; ++i)
#pragma unroll
        for (int j = 0; j < 8; ++j)
          acc[i][j] = mfma16(a[i], b[j], acc[i][j]);
    }
    __syncthreads();
  }

  if (IS_UP) {
    int dbase = n0 >> 1;   // 64 unique d per 128-wide tile
#pragma unroll
    for (int i = 0; i < 2; ++i)
#pragma unroll
      for (int j = 0; j < 4; ++j)
#pragma unroll
        for (int r = 0; r < 4; ++r) {
          int lr = w * 32 + i * 16 + quad * 4 + r;   // C/D: row = quad*4+reg
          int rid = rows_s[lr];
          if (rid >= 0) {
            float g = acc[i][j][r];
            float u = acc[i][j + 4][r];
            float hv = g / (1.f + __expf(-g)) * u;
            hidden[(size_t)rid * DDIM + dbase + j * 16 + lm] = (__bf16)hv;
          }
        }
  } else {
#pragma unroll
    for (int i = 0; i < 2; ++i)
#pragma unroll
      for (int j = 0; j < 8; ++j)
#pragma unroll
        for (int r = 0; r < 4; ++r) {
          int lr = w * 32 + i * 16 + quad * 4 + r;
          int rid = rows_s[lr];
          if (rid >= 0)
            out[(size_t)rid * HDIM + n0 + j * 16 + lm] = acc[i][j][r];
        }
  }
}

// -------- up-GEMM: 640 blocks, ny = b&15 -> XCD = ny%8 (B-tile L2 locality) ------------
__global__ __launch_bounds__(256, 3) void up_kernel(
    const __bf16* __restrict__ xb, const __bf16* __restrict__ wup,
    const int* __restrict__ counts, const int* __restrict__ tok_list,
    __bf16* __restrict__ hidden)
{
  __shared__ __align__(16) char smem[33280];
  __bf16* As = (__bf16*)smem;
  __bf16* Bs = (__bf16*)(smem + 16384);
  int* rows_s = (int*)(smem + 32768);
  int b = blockIdx.x;
  gemm_body<true>(xb, wup, counts, tok_list, hidden, (float*)nullptr,
                  b >> 4, (b & 15) * 128, 0, 1024, As, Bs, rows_s);
}

// -------- down: grid (8 ny, 40 mb, 2 kz) -> D2[kz] plain stores (no atomics) -----------
__global__ __launch_bounds__(256, 3) void down_kernel(
    const __bf16* __restrict__ hidden, const __bf16* __restrict__ wdn,
    const int* __restrict__ counts, const int* __restrict__ tok_list,
    float* __restrict__ d2)
{
  __shared__ __align__(16) char smem[33280];
  __bf16* As = (__bf16*)smem;
  __bf16* Bs = (__bf16*)(smem + 16384);
  int* rows_s = (int*)(smem + 32768);
  int kz = blockIdx.z;
  float* D2 = d2 + (size_t)kz * 2 * NTOK * HDIM;
  gemm_body<false>(hidden, wdn, counts, tok_list, (__bf16*)nullptr, D2,
                   blockIdx.y, blockIdx.x * 128, kz * 512, kz * 512 + 512,
                   As, Bs, rows_s);
}

// -------- combine: out[n] = w1*(D2a[2n]+D2b[2n]) + w2*(D2a[2n+1]+D2b[2n+1]) ------------
__global__ __launch_bounds__(256) void combine_kernel(
    const float* __restrict__ d2, const float2* __restrict__ top_w,
    float* __restrict__ out)
{
  int wave = threadIdx.x >> 6, lane = threadIdx.x & 63;
  int n = blockIdx.x * 4 + wave;
  float2 w = top_w[n];
  const size_t HB = (size_t)2 * NTOK * HDIM;   // kz-buffer stride (floats)
  const f32x4* a0 = (const f32x4*)(d2 + (size_t)(2 * n) * HDIM);
  const f32x4* a1 = (const f32x4*)(d2 + (size_t)(2 * n + 1) * HDIM);
  const f32x4* b0 = (const f32x4*)(d2 + HB + (size_t)(2 * n) * HDIM);
  const f32x4* b1 = (const f32x4*)(d2 + HB + (size_t)(2 * n + 1) * HDIM);
  f32x4* o = (f32x4*)(out + (size_t)n * HDIM);
#pragma unroll
  for (int i = 0; i < 4; ++i) {
    int idx = lane + 64 * i;
    o[idx] = (a0[idx] + b0[idx]) * w.x + (a1[idx] + b1[idx]) * w.y;
  }
}

extern "C" void kernel_launch(void* const* d_in, const int* in_sizes, int n_in,
                              void* d_out, int out_size, void* d_ws, size_t ws_size,
                              hipStream_t stream) {
  const float* x  = (const float*)d_in[0];
  const float* rw = (const float*)d_in[1];
  const float* up = (const float*)d_in[2];
  const float* dw = (const float*)d_in[3];
  float* out = (float*)d_out;

  char* ws = (char*)d_ws;
  int* counts          = (int*)ws;                             // 32 B
  int* tok_list        = (int*)(ws + 4096);                    // 64 KB
  unsigned int* top_pk = (unsigned int*)(ws + (256u << 10));   // 8 KB  @ 256 KB
  float2* top_w        = (float2*)(ws + (272u << 10));         // 16 KB @ 272 KB
  __bf16* xb           = (__bf16*)(ws + (1u << 20));           // 4 MB  @ 1 MB
  __bf16* hidden       = (__bf16*)(ws + (8u << 20));           // 8 MB  @ 8 MB
  __bf16* wup          = (__bf16*)(ws + (16u << 20));          // 32 MB @ 16 MB
  float* d2            = (float*)(ws + (16u << 20));           // 32 MB @ 16 MB (overlays wup; wup dead after up_kernel)
  __bf16* wdn          = (__bf16*)(ws + (48u << 20));          // 16 MB @ 48 MB
  (void)ws_size; (void)n_in; (void)in_sizes; (void)out_size;

  prep_kernel<<<2048, 256, 0, stream>>>(x, rw, up, dw, xb, wup, wdn, top_pk, top_w);
  compact_kernel<<<NEXP, 256, 0, stream>>>(top_pk, counts, tok_list);
  up_kernel<<<640, 256, 0, stream>>>(xb, wup, counts, tok_list, hidden);
  down_kernel<<<dim3(8, MAXMB, 2), 256, 0, stream>>>(
      hidden, wdn, counts, tok_list, d2);
  combine_kernel<<<NTOK / 4, 256, 0, stream>>>(d2, top_w, out);
}